// Round 10
// baseline (97.970 us; speedup 1.0000x reference)
//
#include <hip/hip_runtime.h>

// G=14, B=64, T=2048, H=6
#define Gc 14
#define Hc 6
#define NPc (64*2048)          // B*T points
#define LOG_2PI 1.8378770664093453f

typedef float v2f __attribute__((ext_vector_type(2)));

__device__ __forceinline__ float frsq(float x){ return __builtin_amdgcn_rsqf(x); }

// DPP quad_perm broadcast within lane pairs (1-cycle VALU, no LDS):
//   0xA0 = [0,0,2,2] -> pair gets EVEN lane's value; 0xF5 = [1,1,3,3] -> ODD lane's.
template<int CTRL>
__device__ __forceinline__ float dppf(float x){
    union { float f; int i; } u; u.f = x;
    u.i = __builtin_amdgcn_update_dpp(0, u.i, CTRL, 0xF, 0xF, true);
    return u.f;
}
template<int OQ>
__device__ __forceinline__ float bcast(float x){
    return (OQ == 0) ? dppf<0xA0>(x) : dppf<0xF5>(x);
}

// ---- systolic formulation ----
// The reference's 90 gprods = a 12-stage pipeline (6 phase-1 + 6 phase-2 stages).
// Stage k holds one carry row; rows g=0..13 stream through. Per active stage:
//   emit  x3(carry,row) -> row continues to next stage   (head channel zeroed)
//   carry x4(carry,row)                                  (accumulated)
// Identical op sequence & fp order as the unrolled R7 kernel -> identical outputs.
// Row layout: lane0 v2f banks = cur{01}{23}{45}, lane1 = nxt{01}{23}{45}; b scalar
// duplicated. After stage 5 cur is dead: lane0 bank0 repacked to {b,0} so phase-2
// b-updates ride the packed ops for free.
// Coefs (|r*C|==1 identities): S=rsqrt(C1^2+C2^2), s1=C2*S, s2=C1*S,
// a1=copysign(s1,C1), a2=copysign(s2,C2); x3 = a1*x1 - a2*x2 ; x4 = s2*x1 + s1*x2.
// logC == 0 exactly -> dropped.

struct Coef { float a1, a2, s1, s2; };

template<int OQ, int J, int C>
__device__ __forceinline__ Coef mkcoef(const v2f* cv, const v2f* rv){
    const float C1 = bcast<OQ>(cv[J][C]);    // carry head
    const float C2 = bcast<OQ>(rv[J][C]);    // row head
    const float S  = frsq(fmaf(C1, C1, C2 * C2));   // 1 transcendental per gprod
    Coef c;
    c.s1 = C2 * S; c.s2 = C1 * S;
    c.a1 = copysignf(c.s1, C1);
    c.a2 = copysignf(c.s2, C2);
    return c;
}

__device__ __forceinline__ void rot3(v2f* cv, v2f (&rv)[3], const Coef& c){
    const v2f A1 = {c.a1, c.a1}, A2 = {c.a2, c.a2}, S1 = {c.s1, c.s1}, S2 = {c.s2, c.s2};
#pragma unroll
    for (int j = 0; j < 3; ++j){
        const v2f x = cv[j], y = rv[j];
        rv[j] = __builtin_elementwise_fma(x, A1, -(y * A2));   // emitted row
        cv[j] = __builtin_elementwise_fma(x, S2, y * S1);      // new carry
    }
}

struct St1 { v2f v[3]; float b; };
struct St2 { v2f v[3]; };

// Phase-1 stage K (head = cur[K] on lane0). Guards are wave-uniform (g).
template<int K>
__device__ __forceinline__ void stage_p1(int g, St1& s, v2f (&r)[3], float& rb){
    if (g < K) return;                       // not active yet
    if (g == K){                             // first row -> init carry, consume row
        s.v[0] = r[0]; s.v[1] = r[1]; s.v[2] = r[2]; s.b = rb;
        return;
    }
    const Coef c = mkcoef<0, (K >> 1), (K & 1)>(s.v, r);
    rot3(s.v, r, c);
    const float x = s.b, y = rb;             // bias channel (duplicated scalar)
    rb  = fmaf(x, c.a1, -(y * c.a2));
    s.b = fmaf(x, c.s2,   y * c.s1);
}

// Phase-2 stage K (head = nxt[K] on lane1); lane0 bank0 carries {b,.}, banks 1,2 junk.
template<int K>
__device__ __forceinline__ void stage_p2(int g, St2& s, v2f (&r)[3]){
    constexpr int START = 6 + K;
    if (g < START) return;
    if (g == START){
        s.v[0] = r[0]; s.v[1] = r[1]; s.v[2] = r[2];
        return;
    }
    const Coef c = mkcoef<1, (K >> 1), (K & 1)>(s.v, r);
    rot3(s.v, r, c);
}

// NOTE (toolchain): __launch_bounds__(256, N) caps VGPRs at ~256/N
// (N=4 -> 64 cap -> spill storms R4/R6). N=2 -> 128 cap = 4 waves/SIMD tier.
__global__ void __launch_bounds__(256, 2)
gaussmerge_kernel(const float* __restrict__ cur_in,
                  const float* __restrict__ nxt_in,
                  const float* __restrict__ b_in,
                  float* __restrict__ out)
{
    const int tid = threadIdx.x;
    const int q = tid & 1;                          // 0: cur-owner, 1: nxt-owner
    const int p = blockIdx.x * 128 + (tid >> 1);    // point index

    const float* abase = (q ? nxt_in : cur_in) + (size_t)p * Hc;
    const float* bp    = b_in + p;

    St1 s1[6];
    St2 s2[6];
    float LC = 0.0f;    // valid on lane0; lane1's copy is garbage & discarded

    // prefetch row 0
    v2f nr[3]; float nrb;
    { const v2f* a = (const v2f*)abase; nr[0] = a[0]; nr[1] = a[1]; nr[2] = a[2]; nrb = bp[0]; }

#pragma unroll 1       // keep the body to one copy: ~3 KB, I$-resident
    for (int g = 0; g < Gc; ++g){
        v2f r[3] = {nr[0], nr[1], nr[2]};
        float rb = nrb;
        if (g + 1 < Gc){                            // prefetch next row (1-ahead)
            const v2f* a = (const v2f*)(abase + (size_t)(g + 1) * (NPc * Hc));
            nr[0] = a[0]; nr[1] = a[1]; nr[2] = a[2];
            nrb = bp[(size_t)(g + 1) * NPc];
        }

        stage_p1<0>(g, s1[0], r, rb);
        stage_p1<1>(g, s1[1], r, rb);
        stage_p1<2>(g, s1[2], r, rb);
        stage_p1<3>(g, s1[3], r, rb);
        stage_p1<4>(g, s1[4], r, rb);
        stage_p1<5>(g, s1[5], r, rb);

        // p1 -> p2 transition: cur is fully zeroed/dead; pack b into lane0 bank0.
        if (g >= 6 && q == 0) r[0] = (v2f){rb, 0.0f};

        stage_p2<0>(g, s2[0], r);
        stage_p2<1>(g, s2[1], r);
        stage_p2<2>(g, s2[2], r);
        stage_p2<3>(g, s2[3], r);
        stage_p2<4>(g, s2[4], r);
        stage_p2<5>(g, s2[5], r);

        // rows exiting the pipeline (g=12,13) = leftover slots -> bias norm terms
        if (g >= 12){
            const float bd = r[0].x;                // lane0: b ; lane1: garbage
            LC += -0.5f * (LOG_2PI + bd * bd);
        }
    }

    // ---- drain: phase-1 pops (LC log terms; lane0 values) ----
    LC -= __logf(fabsf(s1[0].v[0].x));
    LC -= __logf(fabsf(s1[1].v[0].y));
    LC -= __logf(fabsf(s1[2].v[1].x));
    LC -= __logf(fabsf(s1[3].v[1].y));
    LC -= __logf(fabsf(s1[4].v[2].x));
    LC -= __logf(fabsf(s1[5].v[2].y));

    // ---- drain: phase-2 carries = kept_n (lane1) / kept_b (lane0) ----
    float* outN = out;                               // (6, B, T, H)
    float* outB = out + (size_t)Hc * NPc * Hc;       // (6, B, T)
    float* outL = outB + (size_t)Hc * NPc;           // (B, T)
#pragma unroll
    for (int k = 0; k < 6; ++k){
        if (q){
            v2f* o = (v2f*)(outN + (size_t)k * (NPc * Hc) + (size_t)p * Hc);
            o[0] = s2[k].v[0]; o[1] = s2[k].v[1]; o[2] = s2[k].v[2];
        } else {
            outB[(size_t)k * NPc + p] = s2[k].v[0].x;
        }
    }
    if (q == 0) outL[p] = LC;
}

extern "C" void kernel_launch(void* const* d_in, const int* in_sizes, int n_in,
                              void* d_out, int out_size, void* d_ws, size_t ws_size,
                              hipStream_t stream) {
    const float* cur = (const float*)d_in[0];
    const float* nxt = (const float*)d_in[1];
    const float* bia = (const float*)d_in[2];
    float* out = (float*)d_out;

    // 2 threads per point: 256-thread blocks cover 128 points each.
    dim3 grid((NPc * 2) / 256), block(256);
    gaussmerge_kernel<<<grid, block, 0, stream>>>(cur, nxt, bia, out);
}

// Round 11
// 29.807 us; speedup vs baseline: 3.2868x; 3.2868x over previous
//
#include <hip/hip_runtime.h>

// G=14, B=64, T=2048, H=6
#define Gc 14
#define Hc 6
#define NPc (64*2048)          // B*T points
#define LOG_2PI 1.8378770664093453f

typedef float v2f __attribute__((ext_vector_type(2)));

__device__ __forceinline__ float frsq(float x){ return __builtin_amdgcn_rsqf(x); }

// DPP quad_perm broadcast within lane pairs (1-cycle VALU, no LDS):
//   0xA0 = [0,0,2,2] -> pair gets EVEN lane's value; 0xF5 = [1,1,3,3] -> ODD lane's.
template<int CTRL>
__device__ __forceinline__ float dppf(float x){
    union { float f; int i; } u; u.f = x;
    u.i = __builtin_amdgcn_update_dpp(0, u.i, CTRL, 0xF, 0xF, true);
    return u.f;
}
template<int OQ>
__device__ __forceinline__ float bcast(float x){
    return (OQ == 0) ? dppf<0xA0>(x) : dppf<0xF5>(x);
}

// Nontemporal 8-byte store (keep the 22 MB output stream out of L2/L3 so the
// 95 MB input set stays Infinity-Cache-resident across replays).
__device__ __forceinline__ void nt_store_v2f(float* p, v2f v){
    union { v2f f; unsigned long long u; } c; c.f = v;
    __builtin_nontemporal_store(c.u, (unsigned long long*)p);
}

// One sweep of N-1 chained gprods.
// Head channel = component C of v2f J on owner lane OQ (cur on lane0 / nxt on lane1).
// Identities (|r*C|==1): x3 = a1*x1 - a2*x2 ; x4 = s2*x1 + s1*x2, with
//   S = rsqrt(C1^2+C2^2), s1=C2*S, s2=C1*S, a1=copysign(s1,C1), a2=copysign(s2,C2).
// logC == 0 exactly -> dropped. Head channel gets x4 = sqrt(C1^2+C2^2) = 1/std4. OK.
// Lane0 st = cur, lane1 st = nxt (one uniform packed stream serves both arrays);
// bb duplicated & bit-identical on both lanes.
template<int J, int C, int N, int OQ>
__device__ __forceinline__ void sweep(v2f (&st)[Gc][3], float (&bb)[Gc]){
#pragma unroll
    for (int i = 0; i < N - 1; ++i){
        const float C1 = bcast<OQ>(st[i][J][C]);
        const float C2 = bcast<OQ>(st[i + 1][J][C]);
        const float S  = frsq(fmaf(C1, C1, C2 * C2));   // 1 transcendental per gprod
        const float s1 = C2 * S, s2 = C1 * S;
        const float a1 = copysignf(s1, C1), a2 = copysignf(s2, C2);
        const v2f A1 = {a1, a1}, A2 = {a2, a2}, S1 = {s1, s1}, S2 = {s2, s2};
        // 3 packed channel-pair updates: 12 v_pk ops cover 6 channels x (cur|nxt)
#pragma unroll
        for (int j = 0; j < 3; ++j){
            const v2f x = st[i][j], y = st[i + 1][j];
            st[i][j]     = __builtin_elementwise_fma(x, A1, -(y * A2));
            st[i + 1][j] = __builtin_elementwise_fma(x, S2, y * S1);
        }
        // bias channel (scalar; bit-identical on both lanes)
        {
            const float x = bb[i], y = bb[i + 1];
            bb[i]     = fmaf(x, a1, -(y * a2));
            bb[i + 1] = fmaf(x, s2, y * s1);
        }
    }
}

// NOTE (toolchain): __launch_bounds__(256, N) caps VGPRs at ~256/N
// (N=4 -> 64 cap -> spill storms R4/R6). N=2 -> 128 cap = 4 waves/SIMD tier;
// grid has 4096 waves = full residency (4/SIMD on 1024 SIMDs). State ~98 floats.
__global__ void __launch_bounds__(256, 2)
gaussmerge_kernel(const float* __restrict__ cur_in,
                  const float* __restrict__ nxt_in,
                  const float* __restrict__ b_in,
                  float* __restrict__ out)
{
    const int tid = threadIdx.x;
    const int q = tid & 1;                          // 0: cur-owner, 1: nxt-owner
    const int p = blockIdx.x * 128 + (tid >> 1);    // point index

    v2f   st[Gc][3];
    float bb[Gc];

    const float* abase = (q ? nxt_in : cur_in) + (size_t)p * Hc;
    const float* bp    = b_in + p;
#pragma unroll
    for (int g = 0; g < Gc; ++g){
        // one 24-B record per lane: dwordx4 + dwordx2 (was 3x dwordx2)
        const float* rec = abase + (size_t)g * (NPc * Hc);
        const float4 A = *(const float4*)rec;
        const float2 B = *(const float2*)(rec + 4);
        st[g][0] = (v2f){A.x, A.y};
        st[g][1] = (v2f){A.z, A.w};
        st[g][2] = (v2f){B.x, B.y};
        bb[g] = bp[(size_t)g * NPc];
    }

    float LC = 0.0f;   // phase-1 log args valid on lane0 only; lane1's LC discarded

    // ---- phase 1: head = cur[k] (lane0); k -> (J=k>>1, C=k&1); n = 14-k ----
    sweep<0, 0, 14, 0>(st, bb); LC -= __logf(fabsf(st[13][0][0]));
    sweep<0, 1, 13, 0>(st, bb); LC -= __logf(fabsf(st[12][0][1]));
    sweep<1, 0, 12, 0>(st, bb); LC -= __logf(fabsf(st[11][1][0]));
    sweep<1, 1, 11, 0>(st, bb); LC -= __logf(fabsf(st[10][1][1]));
    sweep<2, 0, 10, 0>(st, bb); LC -= __logf(fabsf(st[ 9][2][0]));
    sweep<2, 1,  9, 0>(st, bb); LC -= __logf(fabsf(st[ 8][2][1]));

    // ---- phase 2: head = nxt[k] (lane1); n = 8-k; popped slot m = 7-k ----
    float* outN = out;                               // (6, B, T, H)
    float* outB = out + (size_t)Hc * NPc * Hc;       // (6, B, T)
    float* outL = outB + (size_t)Hc * NPc;           // (B, T)

#define PH2(K, J, C, N)                                                         \
    sweep<J, C, N, 1>(st, bb);                                                  \
    {                                                                           \
        constexpr int m = 7 - (K);                                              \
        if (q) {                                                                \
            float* o = outN + (size_t)(K) * (NPc * Hc) + (size_t)p * Hc;        \
            nt_store_v2f(o,     st[m][0]);                                      \
            nt_store_v2f(o + 2, st[m][1]);                                      \
            nt_store_v2f(o + 4, st[m][2]);                                      \
        } else {                                                                \
            __builtin_nontemporal_store(bb[m], outB + (size_t)(K) * NPc + p);   \
        }                                                                       \
    }

    PH2(0, 0, 0, 8)
    PH2(1, 0, 1, 7)
    PH2(2, 1, 0, 6)
    PH2(3, 1, 1, 5)
    PH2(4, 2, 0, 4)
    PH2(5, 2, 1, 3)
#undef PH2

    // ---- epilogue: remaining biases (slots 0,1; identical on both lanes) ----
    LC += -0.5f * (LOG_2PI + bb[0] * bb[0]);
    LC += -0.5f * (LOG_2PI + bb[1] * bb[1]);
    if (q == 0) __builtin_nontemporal_store(LC, outL + p);
}

extern "C" void kernel_launch(void* const* d_in, const int* in_sizes, int n_in,
                              void* d_out, int out_size, void* d_ws, size_t ws_size,
                              hipStream_t stream) {
    const float* cur = (const float*)d_in[0];
    const float* nxt = (const float*)d_in[1];
    const float* bia = (const float*)d_in[2];
    float* out = (float*)d_out;

    // 2 threads per point: 256-thread blocks cover 128 points each.
    dim3 grid((NPc * 2) / 256), block(256);
    gaussmerge_kernel<<<grid, block, 0, stream>>>(cur, nxt, bia, out);
}